// Round 3
// baseline (13955.399 us; speedup 1.0000x reference)
//
#include <hip/hip_runtime.h>
#include <cstdint>
#include <cstddef>

#define TT 512
#define NWG 256
#define SCH0 32
#define NCH0 16
#define SCH1 16
#define NCH1 32

// ---- Workspace layout (BYTE offsets) — identical region sizes to baseline (~165 MiB).
#define OFF_H0   0ul
#define SZ_H0    (512ul*1024ul*64ul*2ul)          /* layer0 out, bf16 (T,1024,B) 64MiB */
#define OFF_OUT  (OFF_H0 + SZ_H0)
#define SZ_OUT   (512ul*512ul*64ul*4ul)           /* l1 fwd+bwd sum fp32; ALSO l0 xw dbuf */
#define OFF_XW1  (OFF_OUT + SZ_OUT)
#define SZ_XW1   (2ul*32ul*2048ul*64ul*4ul)       /* layer1 xw double buffer, 32MiB */
#define OFF_HBUF (OFF_XW1 + SZ_XW1)
#define SZ_HBUF  (2ul*2ul*2ul*512ul*64ul*4ul)     /* [layer][pp][dir][j][b] fp32 */
#define OFF_CST  (OFF_HBUF + SZ_HBUF)
#define SZ_CST   (2ul*2ul*512ul*64ul*4ul)
#define OFF_FLG  (OFF_CST + SZ_CST)
#define SZ_FLG   (2ul*2ul*512ul*128ul*4ul)        /* u32 counters [layer][dir][step][slot] 0->4 */
#define OFF_E    (OFF_FLG + SZ_FLG)
#define SZ_E     (64ul*512ul*4ul)
#define OFF_AT   (OFF_E + SZ_E)
#define SZ_AT    (512ul*64ul*4ul)
#define OFF_POOL (OFF_AT + SZ_AT)
#define SZ_POOL  (512ul*64ul*4ul)

#define SZB0 (2ul*(size_t)SCH0*2048ul*64ul*4ul)   /* 33.5MB l0 xw chunk; 2 fit in SZ_OUT */
#define SZB1 (2ul*(size_t)SCH1*2048ul*64ul*4ul)   /* 16.8MB l1 xw chunk; 2 fit in SZ_XW1 */

#define FUSED_LDS 65536   /* recur: wlds [512][16] 32KB + red [8][16][64] 32KB; 2 blocks/CU */

typedef unsigned long long u64;

__device__ __forceinline__ unsigned short f2bf(float f) {   // RNE bf16
  unsigned u = __float_as_uint(f);
  u += 0x7fffu + ((u >> 16) & 1u);
  return (unsigned short)(u >> 16);
}

// ---- xW GEMM tile: xw[d][sl][g][b] = bias + sum_k X[t][b][k]*W[d][g][k]
// X32 != nullptr -> layer-0 input (fp32, K=256); else h0 bf16 (K=1024).
// Wt columns XOR-swizzled by ((row>>3)&3)<<2: rows 8 apart at stride 68 floats
// land on the SAME bank (8*68 % 32 == 0) -> the 4 gq values per wave were
// 4-way conflicted on EVERY inner read. Swizzle makes them conflict-free.
__device__ __forceinline__ void gemm_tile(const float* __restrict__ X32,
                                          const unsigned short* __restrict__ Xb,
                                          const float* __restrict__ W,
                                          const float* __restrict__ bias,
                                          float* __restrict__ xwout,
                                          int s0, int sch, int gtile, int sl, int d,
                                          float* Wt, float* Xt) {
  const int K = X32 ? 256 : 1024;
  const int tid = threadIdx.x;
  const int sg = s0 + sl;
  const int t = d ? (511 - sg) : sg;
  const int gq = tid >> 4, bq = tid & 15;
  const int g0 = gtile*128 + gq*8;

  float acc[8][4];
  #pragma unroll
  for (int i = 0; i < 8; ++i) {
    const float bv = bias[d*2048 + g0 + i];
    acc[i][0]=bv; acc[i][1]=bv; acc[i][2]=bv; acc[i][3]=bv;
  }
  const float* Wbase = W + ((size_t)d*2048 + gtile*128)*K;

  for (int kc = 0; kc < K; kc += 64) {
    __syncthreads();      // also separates jobs when called in a loop
    #pragma unroll
    for (int i = 0; i < 8; ++i) {
      const int f4 = i*256 + tid;
      const int row = f4 >> 4, kk4 = (f4 & 15) << 2;
      const int kk4s = kk4 ^ (((row >> 3) & 3) << 2);   // swizzled col group
      *(float4*)(Wt + row*68 + kk4s) = *(const float4*)(Wbase + (size_t)row*K + kc + kk4);
    }
    if (X32) {
      const int bb = tid >> 2, kq = tid & 3;
      const float* src = X32 + ((size_t)t*64 + bb)*256 + kc + kq*16;
      #pragma unroll
      for (int i = 0; i < 4; ++i) {
        const float4 v = *(const float4*)(src + i*4);
        const int k = kq*16 + i*4;
        Xt[(k+0)*68 + bb] = v.x;
        Xt[(k+1)*68 + bb] = v.y;
        Xt[(k+2)*68 + bb] = v.z;
        Xt[(k+3)*68 + bb] = v.w;
      }
    } else {
      const unsigned short* Xbase = Xb + (size_t)t*1024*64;
      #pragma unroll
      for (int i = 0; i < 4; ++i) {
        const int idx = i*256 + tid;
        const int k = idx >> 4, b4 = (idx & 15) << 2;
        const uint2 r = *(const uint2*)(Xbase + (size_t)(kc + k)*64 + b4);
        float4 v;
        v.x = __uint_as_float(r.x << 16);
        v.y = __uint_as_float(r.x & 0xffff0000u);
        v.z = __uint_as_float(r.y << 16);
        v.w = __uint_as_float(r.y & 0xffff0000u);
        *(float4*)(Xt + k*68 + b4) = v;
      }
    }
    __syncthreads();
    for (int k4 = 0; k4 < 64; k4 += 4) {
      float4 w[8];
      #pragma unroll
      for (int i = 0; i < 8; ++i) {
        const int row = gq*8 + i;
        const int k4s = k4 ^ (((row >> 3) & 3) << 2);   // same swizzle on read
        w[i] = *(const float4*)(Wt + row*68 + k4s);
      }
      float4 xv[4];
      #pragma unroll
      for (int kk = 0; kk < 4; ++kk) xv[kk] = *(const float4*)(Xt + (k4+kk)*68 + bq*4);
      #pragma unroll
      for (int i = 0; i < 8; ++i) {
        acc[i][0] += w[i].x*xv[0].x + w[i].y*xv[1].x + w[i].z*xv[2].x + w[i].w*xv[3].x;
        acc[i][1] += w[i].x*xv[0].y + w[i].y*xv[1].y + w[i].z*xv[2].y + w[i].w*xv[3].y;
        acc[i][2] += w[i].x*xv[0].z + w[i].y*xv[1].z + w[i].z*xv[2].z + w[i].w*xv[3].z;
        acc[i][3] += w[i].x*xv[0].w + w[i].y*xv[1].w + w[i].z*xv[2].w + w[i].w*xv[3].w;
      }
    }
  }
  float* op = xwout + (((size_t)d*sch + sl)*2048 + g0)*64 + bq*4;
  #pragma unroll
  for (int i = 0; i < 8; ++i)
    *(float4*)(op + (size_t)i*64) = make_float4(acc[i][0],acc[i][1],acc[i][2],acc[i][3]);
}

// standalone GEMM dispatch (layer-0 chunk 0 prologue; layer-1 chunk 0 between layers).
// layer-1 chunk 0 CANNOT be fused into the last layer-0 dispatch: every job reads h0
// rows written by the FINAL layer-0 steps -> in-dispatch race (round-1 failure).
__global__ void __launch_bounds__(256) xw_gemm(const float* __restrict__ X32,
                                               const unsigned short* __restrict__ Xb,
                                               const float* __restrict__ W,
                                               const float* __restrict__ bias,
                                               float* __restrict__ xwout,
                                               int s0, int sch) {
  __shared__ float Wt[128*68];
  __shared__ float Xt[64*68];
  gemm_tile(X32, Xb, W, bias, xwout, s0, sch, blockIdx.x, blockIdx.y, blockIdx.z, Wt, Xt);
}

// exact pairwise reduction order over the 8 k-group partials (numerics-stable
// across refactors): ((g0+g4)+(g2+g6)) + ((g1+g5)+(g3+g7)).
__device__ __forceinline__ float tree8(const float* spb, int off) {
  const float s0 = spb[off         ], s1 = spb[off + 1*1024];
  const float s2 = spb[off + 2*1024], s3 = spb[off + 3*1024];
  const float s4 = spb[off + 4*1024], s5 = spb[off + 5*1024];
  const float s6 = spb[off + 6*1024], s7 = spb[off + 7*1024];
  return ((s0 + s4) + (s2 + s6)) + ((s1 + s5) + (s3 + s7));
}

// ---- Recurrent body (h @ Whh^T). ZERO fences: hbuf + counters accessed ONLY via
// relaxed agent-scope atomics; explicit vmcnt drain before each wave's signal.
// This round: all-wave polling (no post-poll barrier), 4-deep h-load ring,
// per-wave arrival counters (0->4) instead of barrier+flag, deferred h0/outsum
// stores off the critical chain, 2 adjacent barriers per step (was 3 spread).
__device__ __forceinline__ void recur_body(
    const float* __restrict__ Whh, const float* __restrict__ xw,
    char* __restrict__ wsb, int layer, int s0, int sch, float* lds)
{
  float* wlds = lds;          // [512][16] fp32 weights (k-major), 32KB
  float* red  = lds + 8192;   // [8][16][64] partials, 32KB

  unsigned short* h0 = (unsigned short*)(wsb + OFF_H0);
  float* outsum  = (float*)(wsb + OFF_OUT);
  float* hbuf    = (float*)(wsb + OFF_HBUF) + (size_t)layer*131072;
  float* cstore  = (float*)(wsb + OFF_CST);
  unsigned* flg  = (unsigned*)(wsb + OFF_FLG);

  const int tid = threadIdx.x;
  const int d     = blockIdx.x >> 7;
  const int slot  = blockIdx.x & 127;
  const int jbase = slot << 2;

  const int kg = tid >> 5;
  const int bq = tid & 31;
  const int b0col = bq << 1;
  const int b2  = tid & 63;
  const int jj2 = tid >> 6;

  __builtin_amdgcn_s_setprio(1);   // recurrence waves preferred over co-resident gemm waves

  // stage Whh rows into [k][16] (lr = g*4+jj): lane -> lr, iterate k (2-way free)
  {
    const int lr2 = tid & 15, k2 = tid >> 4;
    const int row2 = (lr2 >> 2)*512 + jbase + (lr2 & 3);
    const float* srch = Whh + ((size_t)d*2048 + row2)*512;
    for (int k = k2; k < 512; k += 16)
      wlds[k*16 + lr2] = srch[k];
  }
  float creg = cstore[((size_t)(layer*2 + d)*512 + jbase + jj2)*64 + b2];
  __syncthreads();

  const unsigned fbase = (unsigned)(layer*2 + d) * 512u;
  const u64 TGT = 0x0000000400000004ull;   // both adjacent counters == 4

  for (int sl = 0; sl < sch; ++sl) {
    const int sg = s0 + sl;
    const int t_in = d ? (511 - sg) : sg;

    // xw preacts are independent of h: issue before the poll so HBM latency
    // hides under flag-wait instead of sitting in the epilogue.
    const float* xwp = xw + ((size_t)(d*sch + sl)*2048 + (size_t)(jbase + jj2))*64 + b2;
    const float px0 = xwp[0];
    const float px1 = xwp[512*64];
    const float px2 = xwp[1024*64];
    const float px3 = xwp[1536*64];

    if (sg > 0) {
      // EVERY wave polls all 128 slot counters (2 per lane via u64 load); each
      // wave proceeds the moment data is ready -> no post-poll barrier.
      const u64* pp = (const u64*)(flg + (size_t)(fbase + (unsigned)sg - 1u)*128) + b2;
      while (__hip_atomic_load(pp, __ATOMIC_RELAXED, __HIP_MEMORY_SCOPE_AGENT) != TGT)
        __builtin_amdgcn_s_sleep(1);
      __asm__ volatile("" ::: "memory");   // keep h loads after poll exit
    }
    const float* hin = hbuf + ((sg & 1)*2 + d)*32768;

    float acc[16][2];
    #pragma unroll
    for (int i = 0; i < 16; ++i) { acc[i][0] = 0.0f; acc[i][1] = 0.0f; }

    // h loads: 8B relaxed agent atomics, 4-deep ring (4 batches = ~2048cy of
    // compute in flight > ~1000cy fabric latency -> fully hidden after batch 0).
    const int kb0 = kg << 6;
    u64 ring[4][8];
    #pragma unroll
    for (int c = 0; c < 4; ++c) {
      #pragma unroll
      for (int kk = 0; kk < 8; ++kk)
        ring[c][kk] = __hip_atomic_load((const u64*)(hin + (size_t)(kb0 + c*8 + kk)*64 + b0col),
                                        __ATOMIC_RELAXED, __HIP_MEMORY_SCOPE_AGENT);
    }
    #pragma unroll
    for (int ch = 0; ch < 8; ++ch) {
      u64 cu[8];
      #pragma unroll
      for (int kk = 0; kk < 8; ++kk) cu[kk] = ring[ch & 3][kk];
      if (ch < 4) {   // prefetch batch ch+4 into the slot just freed
        const int kbp = kb0 + ((ch + 4) << 3);
        #pragma unroll
        for (int kk = 0; kk < 8; ++kk)
          ring[ch & 3][kk] = __hip_atomic_load((const u64*)(hin + (size_t)(kbp + kk)*64 + b0col),
                                               __ATOMIC_RELAXED, __HIP_MEMORY_SCOPE_AGENT);
      }
      const int kb = kb0 + (ch << 3);
      #pragma unroll
      for (int kk = 0; kk < 8; ++kk) {
        const float* wk = wlds + (size_t)(kb + kk)*16;
        const float4 w0 = *(const float4*)(wk);
        const float4 w1 = *(const float4*)(wk + 4);
        const float4 w2 = *(const float4*)(wk + 8);
        const float4 w3 = *(const float4*)(wk + 12);
        const float a0 = __uint_as_float((unsigned)(cu[kk] & 0xffffffffull));
        const float a1 = __uint_as_float((unsigned)(cu[kk] >> 32));
        acc[ 0][0] += w0.x*a0; acc[ 0][1] += w0.x*a1;
        acc[ 1][0] += w0.y*a0; acc[ 1][1] += w0.y*a1;
        acc[ 2][0] += w0.z*a0; acc[ 2][1] += w0.z*a1;
        acc[ 3][0] += w0.w*a0; acc[ 3][1] += w0.w*a1;
        acc[ 4][0] += w1.x*a0; acc[ 4][1] += w1.x*a1;
        acc[ 5][0] += w1.y*a0; acc[ 5][1] += w1.y*a1;
        acc[ 6][0] += w1.z*a0; acc[ 6][1] += w1.z*a1;
        acc[ 7][0] += w1.w*a0; acc[ 7][1] += w1.w*a1;
        acc[ 8][0] += w2.x*a0; acc[ 8][1] += w2.x*a1;
        acc[ 9][0] += w2.y*a0; acc[ 9][1] += w2.y*a1;
        acc[10][0] += w2.z*a0; acc[10][1] += w2.z*a1;
        acc[11][0] += w2.w*a0; acc[11][1] += w2.w*a1;
        acc[12][0] += w3.x*a0; acc[12][1] += w3.x*a1;
        acc[13][0] += w3.y*a0; acc[13][1] += w3.y*a1;
        acc[14][0] += w3.z*a0; acc[14][1] += w3.z*a1;
        acc[15][0] += w3.w*a0; acc[15][1] += w3.w*a1;
      }
    }

    // flat reduction dump, B1, tree-order consumer sum, B2 (red reuse guard).
    {
      float* dst = red + kg*1024 + b0col;
      #pragma unroll
      for (int lr = 0; lr < 16; ++lr)
        *(float2*)(dst + lr*64) = make_float2(acc[lr][0], acc[lr][1]);
    }
    __syncthreads();   // B1: partials visible

    float pi, pf, pg, po;
    {
      const float* spb = red + jj2*64 + b2;
      pi = tree8(spb, 0)      + px0;
      pf = tree8(spb, 4*64)   + px1;
      pg = tree8(spb, 8*64)   + px2;
      po = tree8(spb, 12*64)  + px3;
    }
    __syncthreads();   // B2: all reads of red done -> next step may dump

    {
      const float iv = 1.0f/(1.0f + __expf(-pi));
      const float fv = 1.0f/(1.0f + __expf(-pf));
      const float gv = tanhf(pg);
      const float ov = 1.0f/(1.0f + __expf(-po));
      float cc2 = fv*creg + iv*gv;
      cc2 = fminf(fmaxf(cc2, -100.0f), 100.0f);
      creg = cc2;
      const float h = ov*tanhf(cc2);
      float* hop = hbuf + (((sg & 1) ^ 1)*2 + d)*32768 + (jbase + jj2)*64 + b2;
      __hip_atomic_store(hop, h, __ATOMIC_RELAXED, __HIP_MEMORY_SCOPE_AGENT);
      // per-wave signal: drain THIS wave's stores, then lane 0 bumps the slot
      // counter. Consumers proceed at ==4. No block barrier on this edge.
      __asm__ volatile("s_waitcnt vmcnt(0)" ::: "memory");
      if ((tid & 63) == 0)
        __hip_atomic_fetch_add(flg + (size_t)(fbase + (unsigned)sg)*128 + slot, 1u,
                               __ATOMIC_RELAXED, __HIP_MEMORY_SCOPE_AGENT);
      // deferred: consumed only across dispatch boundaries -> off critical path
      if (layer == 0) {
        h0[(size_t)t_in*65536 + (size_t)(d*512 + jbase + jj2)*64 + b2] = f2bf(h);
      } else {
        atomicAdd(&outsum[(size_t)t_in*32768 + (size_t)(jbase + jj2)*64 + b2], h);
      }
    }
  }
  cstore[((size_t)(layer*2 + d)*512 + jbase + jj2)*64 + b2] = creg;
}

// ---- Fused dispatch: blocks 0..255 = recurrence; blocks 256..511 = next-chunk GEMM.
// GEMM half never polls -> no deadlock. 2 blocks/CU guaranteed (64KB+64KB LDS,
// VGPR capped by launch_bounds(256,2)) -> all 256 recurrence WGs co-resident.
__global__ void __launch_bounds__(256, 2) fused_step(
    const float* __restrict__ Whh, const float* __restrict__ xw_cur,
    float* __restrict__ xw_next,
    const float* __restrict__ gX32, const unsigned short* __restrict__ gXb,
    const float* __restrict__ gW, const float* __restrict__ gB,
    char* __restrict__ wsb,
    int rlayer, int rs0, int rsch,
    int gs0, int gsch, int gnjobs)
{
  extern __shared__ float lds[];
  if (blockIdx.x < NWG) {
    recur_body(Whh, xw_cur, wsb, rlayer, rs0, rsch, lds);
  } else {
    const int wg = blockIdx.x - NWG;
    float* Wt = lds;            // [128][68]
    float* Xt = lds + 128*68;   // [64][68]
    const int half = gnjobs >> 1;
    for (int job = wg; job < gnjobs; job += NWG) {
      const int dd  = (job >= half) ? 1 : 0;
      const int rem = job - (dd ? half : 0);
      const int sl  = rem >> 4;
      const int gt  = rem & 15;
      gemm_tile(gX32, gXb, gW, gB, xw_next, gs0, gsch, gt, sl, dd, Wt, Xt);
    }
  }
}

// ---- attention / output chain ----
__global__ void __launch_bounds__(256) attn_logits(const float* __restrict__ outsum,
                                                   const float* __restrict__ Wa,
                                                   const float* __restrict__ ba,
                                                   float* __restrict__ e) {
  __shared__ float part[4*64];
  const int t = blockIdx.x;
  const int b = threadIdx.x & 63, jq = threadIdx.x >> 6;
  const float* base = outsum + (size_t)t * 512 * 64;
  float acc = 0.0f;
  for (int j = jq*128; j < jq*128 + 128; ++j)
    acc += base[j*64 + b] * Wa[j];
  part[jq*64 + b] = acc;
  __syncthreads();
  if (threadIdx.x < 64) {
    const int bb = threadIdx.x;
    e[bb*512 + t] = part[0*64+bb] + part[1*64+bb] + part[2*64+bb] + part[3*64+bb] + ba[0];
  }
}

__global__ void __launch_bounds__(256) attn_softmax(const float* __restrict__ e,
                                                    float* __restrict__ attn,
                                                    float* __restrict__ aT) {
  __shared__ float red[256];
  const int b = blockIdx.x, tid = threadIdx.x;
  const float v0 = e[b*512 + tid];
  const float v1 = e[b*512 + 256 + tid];
  red[tid] = fmaxf(v0, v1);
  __syncthreads();
  for (int st = 128; st; st >>= 1) { if (tid < st) red[tid] = fmaxf(red[tid], red[tid+st]); __syncthreads(); }
  const float M = red[0];
  __syncthreads();
  const float e0 = __expf(v0 - M), e1 = __expf(v1 - M);
  red[tid] = e0 + e1;
  __syncthreads();
  for (int st = 128; st; st >>= 1) { if (tid < st) red[tid] += red[tid+st]; __syncthreads(); }
  const float inv = 1.0f / red[0];
  const float a0 = e0*inv, a1 = e1*inv;
  attn[b*512 + tid]       = a0;
  attn[b*512 + 256 + tid] = a1;
  aT[tid*64 + b]       = a0;
  aT[(256+tid)*64 + b] = a1;
}

__global__ void __launch_bounds__(256) attn_pool(const float* __restrict__ outsum,
                                                 const float* __restrict__ aT,
                                                 float* __restrict__ pooled) {
  const int tid = threadIdx.x;
  const int b = tid & 63, jj = tid >> 6;
  const int j = blockIdx.x*4 + jj;
  float acc = 0.0f;
  #pragma unroll 4
  for (int t = 0; t < 512; ++t)
    acc += aT[t*64 + b] * outsum[((size_t)t*512 + j)*64 + b];
  pooled[j*64 + b] = acc;
}

__global__ void __launch_bounds__(128) pred_kern(const float* __restrict__ pooled,
                                                 const float* __restrict__ Wo,
                                                 const float* __restrict__ bo,
                                                 float* __restrict__ out) {
  const int b = blockIdx.x, o = threadIdx.x;
  float acc = bo[o];
  const float* wr = Wo + o*512;
  #pragma unroll 4
  for (int j = 0; j < 512; j += 4) {
    const float4 w = *(const float4*)(wr + j);
    acc += w.x*pooled[(j+0)*64 + b] + w.y*pooled[(j+1)*64 + b]
         + w.z*pooled[(j+2)*64 + b] + w.w*pooled[(j+3)*64 + b];
  }
  out[b*128 + o] = acc;
}

extern "C" void kernel_launch(void* const* d_in, const int* in_sizes, int n_in,
                              void* d_out, int out_size, void* d_ws, size_t ws_size,
                              hipStream_t stream) {
  (void)in_sizes; (void)n_in; (void)out_size; (void)ws_size;
  const float* x    = (const float*)d_in[0];
  const float* Wih0 = (const float*)d_in[1];
  const float* Whh0 = (const float*)d_in[2];
  const float* b0   = (const float*)d_in[3];
  const float* Wih1 = (const float*)d_in[4];
  const float* Whh1 = (const float*)d_in[5];
  const float* b1   = (const float*)d_in[6];
  const float* Wa   = (const float*)d_in[7];
  const float* ba   = (const float*)d_in[8];
  const float* Wo   = (const float*)d_in[9];
  const float* bo   = (const float*)d_in[10];
  float* out = (float*)d_out;
  char* wsb  = (char*)d_ws;

  // zero hbuf + cstore + counters (contiguous)
  hipMemsetAsync(wsb + OFF_HBUF, 0, SZ_HBUF + SZ_CST + SZ_FLG, stream);

  float* xw0[2] = { (float*)(wsb + OFF_OUT), (float*)(wsb + OFF_OUT + SZB0) };
  float* xw1[2] = { (float*)(wsb + OFF_XW1), (float*)(wsb + OFF_XW1 + SZB1) };
  const unsigned short* h0p = (const unsigned short*)(wsb + OFF_H0);

  // layer-0 chunk-0 xw prologue
  xw_gemm<<<dim3(16, SCH0, 2), 256, 0, stream>>>(x, nullptr, Wih0, b0, xw0[0], 0, SCH0);

  // layer 0: fused recurrence + next-chunk GEMM (last dispatch runs no gemm)
  for (int c = 0; c < NCH0; ++c) {
    const bool last = (c == NCH0 - 1);
    fused_step<<<dim3(2*NWG), dim3(256), FUSED_LDS, stream>>>(
        Whh0, xw0[c & 1], xw0[(c + 1) & 1],
        x, nullptr, Wih0, b0,
        wsb, 0, c*SCH0, SCH0,
        (c + 1)*SCH0, SCH0, last ? 0 : 16*SCH0*2);
  }

  // layer-1 chunk-0 xw (needs ALL of h0 -> standalone, dispatch-ordered)
  xw_gemm<<<dim3(16, SCH1, 2), 256, 0, stream>>>(nullptr, h0p, Wih1, b1, xw1[0], 0, SCH1);

  // outsum becomes live now; zero it (xw0 double buffer no longer needed)
  hipMemsetAsync(wsb + OFF_OUT, 0, SZ_OUT, stream);

  // layer 1
  for (int c = 0; c < NCH1; ++c) {
    const bool last = (c == NCH1 - 1);
    fused_step<<<dim3(2*NWG), dim3(256), FUSED_LDS, stream>>>(
        Whh1, xw1[c & 1], xw1[(c + 1) & 1],
        nullptr, h0p, Wih1, b1,
        wsb, 1, c*SCH1, SCH1,
        (c + 1)*SCH1, SCH1, last ? 0 : 16*SCH1*2);
  }

  attn_logits <<<512, 256, 0, stream>>>((float*)(wsb + OFF_OUT), Wa, ba, (float*)(wsb + OFF_E));
  attn_softmax<<< 64, 256, 0, stream>>>((float*)(wsb + OFF_E), out + 8192, (float*)(wsb + OFF_AT));
  attn_pool   <<<128, 256, 0, stream>>>((float*)(wsb + OFF_OUT), (float*)(wsb + OFF_AT),
                                        (float*)(wsb + OFF_POOL));
  pred_kern   <<< 64, 128, 0, stream>>>((float*)(wsb + OFF_POOL), Wo, bo, out);
}

// Round 4
// 9056.974 us; speedup vs baseline: 1.5408x; 1.5408x over previous
//
#include <hip/hip_runtime.h>
#include <cstdint>
#include <cstddef>

#define TT 512
#define NWG 256
#define SCH0 32
#define NCH0 16
#define SCH1 16
#define NCH1 32

// ---- Workspace layout (BYTE offsets) — identical region sizes to baseline (~165 MiB).
#define OFF_H0   0ul
#define SZ_H0    (512ul*1024ul*64ul*2ul)          /* layer0 out, bf16 (T,1024,B) 64MiB */
#define OFF_OUT  (OFF_H0 + SZ_H0)
#define SZ_OUT   (512ul*512ul*64ul*4ul)           /* l1 fwd+bwd sum fp32; ALSO l0 xw dbuf */
#define OFF_XW1  (OFF_OUT + SZ_OUT)
#define SZ_XW1   (2ul*32ul*2048ul*64ul*4ul)       /* layer1 xw double buffer, 32MiB */
#define OFF_HBUF (OFF_XW1 + SZ_XW1)
#define SZ_HBUF  (2ul*2ul*2ul*512ul*64ul*4ul)     /* [layer][pp][dir] packed-h u32 [k/2][b][2] */
#define OFF_CST  (OFF_HBUF + SZ_HBUF)
#define SZ_CST   (2ul*2ul*512ul*64ul*4ul)
#define OFF_FLG  (OFF_CST + SZ_CST)
#define SZ_FLG   (2ul*2ul*512ul*128ul*4ul)        /* u32 flags [layer][dir][step][slot] */
#define OFF_E    (OFF_FLG + SZ_FLG)
#define SZ_E     (64ul*512ul*4ul)
#define OFF_AT   (OFF_E + SZ_E)
#define SZ_AT    (512ul*64ul*4ul)
#define OFF_POOL (OFF_AT + SZ_AT)
#define SZ_POOL  (512ul*64ul*4ul)

#define SZB0 (2ul*(size_t)SCH0*2048ul*64ul*4ul)   /* 33.5MB l0 xw chunk; 2 fit in SZ_OUT */
#define SZB1 (2ul*(size_t)SCH1*2048ul*64ul*4ul)   /* 16.8MB l1 xw chunk; 2 fit in SZ_XW1 */

#define FUSED_LDS 53248   /* recur: A-frags 32KB; gemm: Wt+Xt 52.2KB */

typedef unsigned long long u64;
typedef __attribute__((ext_vector_type(8))) short short8v;   // bf16x8 MFMA frag (4 VGPR)
typedef __attribute__((ext_vector_type(4))) float f32x4;     // MFMA C/D frag

#define AHL(p) __hip_atomic_load((p), __ATOMIC_RELAXED, __HIP_MEMORY_SCOPE_AGENT)

__device__ __forceinline__ unsigned short f2bf(float f) {   // RNE bf16
  unsigned u = __float_as_uint(f);
  u += 0x7fffu + ((u >> 16) & 1u);
  return (unsigned short)(u >> 16);
}

// ---- xW GEMM tile: xw[d][sl][g][b] = bias + sum_k X[t][b][k]*W[d][g][k]
// X32 != nullptr -> layer-0 input (fp32, K=256); else h0 bf16 (K=1024).
__device__ __forceinline__ void gemm_tile(const float* __restrict__ X32,
                                          const unsigned short* __restrict__ Xb,
                                          const float* __restrict__ W,
                                          const float* __restrict__ bias,
                                          float* __restrict__ xwout,
                                          int s0, int sch, int gtile, int sl, int d,
                                          float* Wt, float* Xt) {
  const int K = X32 ? 256 : 1024;
  const int tid = threadIdx.x;
  const int sg = s0 + sl;
  const int t = d ? (511 - sg) : sg;
  const int gq = tid >> 4, bq = tid & 15;
  const int g0 = gtile*128 + gq*8;

  float acc[8][4];
  #pragma unroll
  for (int i = 0; i < 8; ++i) {
    const float bv = bias[d*2048 + g0 + i];
    acc[i][0]=bv; acc[i][1]=bv; acc[i][2]=bv; acc[i][3]=bv;
  }
  const float* Wbase = W + ((size_t)d*2048 + gtile*128)*K;

  for (int kc = 0; kc < K; kc += 64) {
    __syncthreads();      // also separates jobs when called in a loop
    #pragma unroll
    for (int i = 0; i < 8; ++i) {
      const int f4 = i*256 + tid;
      const int row = f4 >> 4, kk4 = (f4 & 15) << 2;
      const int kk4s = kk4 ^ (((row >> 3) & 3) << 2);
      *(float4*)(Wt + row*68 + kk4s) = *(const float4*)(Wbase + (size_t)row*K + kc + kk4);
    }
    if (X32) {
      const int bb = tid >> 2, kq = tid & 3;
      const float* src = X32 + ((size_t)t*64 + bb)*256 + kc + kq*16;
      #pragma unroll
      for (int i = 0; i < 4; ++i) {
        const float4 v = *(const float4*)(src + i*4);
        const int k = kq*16 + i*4;
        Xt[(k+0)*68 + bb] = v.x;
        Xt[(k+1)*68 + bb] = v.y;
        Xt[(k+2)*68 + bb] = v.z;
        Xt[(k+3)*68 + bb] = v.w;
      }
    } else {
      const unsigned short* Xbase = Xb + (size_t)t*1024*64;
      #pragma unroll
      for (int i = 0; i < 4; ++i) {
        const int idx = i*256 + tid;
        const int k = idx >> 4, b4 = (idx & 15) << 2;
        const uint2 r = *(const uint2*)(Xbase + (size_t)(kc + k)*64 + b4);
        float4 v;
        v.x = __uint_as_float(r.x << 16);
        v.y = __uint_as_float(r.x & 0xffff0000u);
        v.z = __uint_as_float(r.y << 16);
        v.w = __uint_as_float(r.y & 0xffff0000u);
        *(float4*)(Xt + k*68 + b4) = v;
      }
    }
    __syncthreads();
    for (int k4 = 0; k4 < 64; k4 += 4) {
      float4 w[8];
      #pragma unroll
      for (int i = 0; i < 8; ++i) {
        const int row = gq*8 + i;
        const int k4s = k4 ^ (((row >> 3) & 3) << 2);
        w[i] = *(const float4*)(Wt + row*68 + k4s);
      }
      float4 xv[4];
      #pragma unroll
      for (int kk = 0; kk < 4; ++kk) xv[kk] = *(const float4*)(Xt + (k4+kk)*68 + bq*4);
      #pragma unroll
      for (int i = 0; i < 8; ++i) {
        acc[i][0] += w[i].x*xv[0].x + w[i].y*xv[1].x + w[i].z*xv[2].x + w[i].w*xv[3].x;
        acc[i][1] += w[i].x*xv[0].y + w[i].y*xv[1].y + w[i].z*xv[2].y + w[i].w*xv[3].y;
        acc[i][2] += w[i].x*xv[0].z + w[i].y*xv[1].z + w[i].z*xv[2].z + w[i].w*xv[3].z;
        acc[i][3] += w[i].x*xv[0].w + w[i].y*xv[1].w + w[i].z*xv[2].w + w[i].w*xv[3].w;
      }
    }
  }
  float* op = xwout + (((size_t)d*sch + sl)*2048 + g0)*64 + bq*4;
  #pragma unroll
  for (int i = 0; i < 8; ++i)
    *(float4*)(op + (size_t)i*64) = make_float4(acc[i][0],acc[i][1],acc[i][2],acc[i][3]);
}

// standalone GEMM dispatch (layer-0 chunk 0 prologue; layer-1 chunk 0 between layers).
__global__ void __launch_bounds__(256) xw_gemm(const float* __restrict__ X32,
                                               const unsigned short* __restrict__ Xb,
                                               const float* __restrict__ W,
                                               const float* __restrict__ bias,
                                               float* __restrict__ xwout,
                                               int s0, int sch) {
  __shared__ float Wt[128*68];
  __shared__ float Xt[64*68];
  gemm_tile(X32, Xb, W, bias, xwout, s0, sch, blockIdx.x, blockIdx.y, blockIdx.z, Wt, Xt);
}

// ---- Recurrent body: gates[16 rows][64 b] = Whh16 x h  via MFMA 16x16x32 bf16,
// split-bf16 (value+residual) operands => fp32-grade precision (err ~1e-5).
// A rows m = jj*4+g so the C fragment (col=lane&15, row=(lane>>4)*4+reg) gives
// each lane ALL FOUR GATES of one j => lane-local epilogue, NO LDS reduction,
// 2 barriers/step. Handshake = proven round-2 mechanics (tid<128 poll + B0,
// syncthreads drain, single tid0 flag store). h packed (bf16val<<16)|bf16res
// in k-pair-major layout: dword idx = (k>>1)*128 + b*2 + (k&1)  => producer
// stores and consumer u64 loads are fully line-coalesced.
__device__ __forceinline__ void recur_body(
    const float* __restrict__ Whh, const float* __restrict__ xw,
    char* __restrict__ wsb, int layer, int s0, int sch, float* lds)
{
  unsigned short* alds = (unsigned short*)lds;   // [2 part][16 ks][4 oct][16 slot][8 e] bf16 = 32KB

  unsigned short* h0 = (unsigned short*)(wsb + OFF_H0);
  float* outsum  = (float*)(wsb + OFF_OUT);
  unsigned* hbase = (unsigned*)(wsb + OFF_HBUF) + (size_t)layer*131072;
  float* cstore  = (float*)(wsb + OFF_CST);
  unsigned* flg  = (unsigned*)(wsb + OFF_FLG);

  const int tid = threadIdx.x;
  const int d     = blockIdx.x >> 7;
  const int slot  = blockIdx.x & 127;
  const int jbase = slot << 2;

  const int w    = tid >> 6;          // wave -> 16-batch column block
  const int lane = tid & 63;
  const int lhi  = lane >> 4;
  const int lcol = lane & 15;
  const int jj   = lhi;               // epilogue j index (C row group)
  const int b    = w*16 + lcol;       // epilogue batch (C col)

  __builtin_amdgcn_s_setprio(1);      // recurrence waves preferred over gemm waves

  // stage Whh as split-bf16 MFMA A-fragments. element (m,k) at
  // [part][k>>5][(k>>3)&3][m ^ ((k>>3)&3)][k&7]  (XOR de-conflicts b128 reads)
  for (int m = 0; m < 16; ++m) {
    const int g = m & 3, j = m >> 2;
    const float* src = Whh + ((size_t)d*2048 + g*512 + jbase + j)*512;
    for (int k = tid; k < 512; k += 256) {
      const float wv = src[k];
      const unsigned short wb = f2bf(wv);
      const unsigned short wr = f2bf(wv - __uint_as_float((unsigned)wb << 16));
      const int oct = (k >> 3) & 3;
      const int idx = (((k >> 5)*4 + oct)*16 + (m ^ oct))*8 + (k & 7);
      alds[idx] = wb;
      alds[8192 + idx] = wr;
    }
  }
  float creg = cstore[((size_t)(layer*2 + d)*512 + jbase + jj)*64 + b];
  __syncthreads();

  const unsigned fbase = (unsigned)(layer*2 + d) * 512u;

  for (int sl = 0; sl < sch; ++sl) {
    const int sg = s0 + sl;
    const int t_in = d ? (511 - sg) : sg;

    // xw preacts are h-independent: issue before the poll (latency hides there)
    const float* xwp = xw + ((size_t)(d*sch + sl)*2048 + (size_t)(jbase + jj))*64 + b;
    const float px0 = xwp[0];
    const float px1 = xwp[32768];
    const float px2 = xwp[65536];
    const float px3 = xwp[98304];

    if (sg > 0) {
      if (tid < 128) {   // proven round-2 poll: 1 flag/lane, relaxed agent
        unsigned* p = &flg[(size_t)(fbase + (unsigned)sg - 1u)*128 + tid];
        while (AHL(p) == 0u) __builtin_amdgcn_s_sleep(1);
      }
      __syncthreads();   // B0
    }

    const u64* hsrc = (const u64*)(hbase + ((sg & 1)*2 + d)*32768);

    // B operand ring: per ks, 4 u64 = 8 packed dwords = elements e0..7 for col b.
    u64 ring[8][4];
    #pragma unroll
    for (int ks = 0; ks < 8; ++ks) {
      const size_t hb0 = (size_t)((ks*4 + lhi)*4)*64 + b;
      ring[ks][0] = AHL(hsrc + hb0);
      ring[ks][1] = AHL(hsrc + hb0 + 64);
      ring[ks][2] = AHL(hsrc + hb0 + 128);
      ring[ks][3] = AHL(hsrc + hb0 + 192);
    }

    f32x4 acc = {0.f, 0.f, 0.f, 0.f};
    #pragma unroll
    for (int ks = 0; ks < 16; ++ks) {
      const u64 q0 = ring[ks & 7][0], q1 = ring[ks & 7][1];
      const u64 q2 = ring[ks & 7][2], q3 = ring[ks & 7][3];
      if (ks < 8) {
        const size_t hb2 = (size_t)(((ks + 8)*4 + lhi)*4)*64 + b;
        ring[ks][0] = AHL(hsrc + hb2);
        ring[ks][1] = AHL(hsrc + hb2 + 64);
        ring[ks][2] = AHL(hsrc + hb2 + 128);
        ring[ks][3] = AHL(hsrc + hb2 + 192);
      }
      // unpack packed (hb<<16)|rb dwords into value/residual bf16 fragments
      union { unsigned u[4]; short8v v; } hb, rb;
      hb.u[0] = __builtin_amdgcn_perm((unsigned)(q0 >> 32), (unsigned)q0, 0x07060302u);
      rb.u[0] = __builtin_amdgcn_perm((unsigned)(q0 >> 32), (unsigned)q0, 0x05040100u);
      hb.u[1] = __builtin_amdgcn_perm((unsigned)(q1 >> 32), (unsigned)q1, 0x07060302u);
      rb.u[1] = __builtin_amdgcn_perm((unsigned)(q1 >> 32), (unsigned)q1, 0x05040100u);
      hb.u[2] = __builtin_amdgcn_perm((unsigned)(q2 >> 32), (unsigned)q2, 0x07060302u);
      rb.u[2] = __builtin_amdgcn_perm((unsigned)(q2 >> 32), (unsigned)q2, 0x05040100u);
      hb.u[3] = __builtin_amdgcn_perm((unsigned)(q3 >> 32), (unsigned)q3, 0x07060302u);
      rb.u[3] = __builtin_amdgcn_perm((unsigned)(q3 >> 32), (unsigned)q3, 0x05040100u);
      const int abase = ((ks*4 + lhi)*16 + (lcol ^ lhi))*8;
      const short8v ab = *(const short8v*)(alds + abase);
      const short8v ar = *(const short8v*)(alds + 8192 + abase);
      acc = __builtin_amdgcn_mfma_f32_16x16x32_bf16(ab, hb.v, acc, 0, 0, 0);
      acc = __builtin_amdgcn_mfma_f32_16x16x32_bf16(ab, rb.v, acc, 0, 0, 0);
      acc = __builtin_amdgcn_mfma_f32_16x16x32_bf16(ar, hb.v, acc, 0, 0, 0);
      // dropped Wr*rb term: ~4e-6 relative
    }

    // epilogue: lane-local gates (acc[r] = gate r of j = jbase+jj, batch b)
    const float pi = acc[0] + px0;
    const float pf = acc[1] + px1;
    const float pg = acc[2] + px2;
    const float po = acc[3] + px3;
    const float iv = 1.0f/(1.0f + __expf(-pi));
    const float fv = 1.0f/(1.0f + __expf(-pf));
    const float gv = tanhf(pg);
    const float ov = 1.0f/(1.0f + __expf(-po));
    float cc2 = fv*creg + iv*gv;
    cc2 = fminf(fmaxf(cc2, -100.0f), 100.0f);
    creg = cc2;
    const float h = ov*tanhf(cc2);

    const unsigned short hb16 = f2bf(h);
    const unsigned short rb16 = f2bf(h - __uint_as_float((unsigned)hb16 << 16));
    const unsigned hpk = ((unsigned)hb16 << 16) | (unsigned)rb16;
    unsigned* hout = hbase + (((sg & 1) ^ 1)*2 + d)*32768;
    const int kj = jbase + jj;
    __hip_atomic_store(hout + ((size_t)(kj >> 1)*128 + b*2 + (kj & 1)), hpk,
                       __ATOMIC_RELAXED, __HIP_MEMORY_SCOPE_AGENT);

    __syncthreads();   // Bend: drains each wave's vmcnt -> h stores ACKed
    if (tid == 0)
      __hip_atomic_store(&flg[(size_t)(fbase + (unsigned)sg)*128 + slot], 1u,
                         __ATOMIC_RELAXED, __HIP_MEMORY_SCOPE_AGENT);
    // deferred: consumed only across dispatch boundaries -> off the critical
    // edge; their ACK folds into the NEXT step's Bend (poll interval >> ACK).
    if (layer == 0) {
      h0[(size_t)t_in*65536 + (size_t)(d*512 + kj)*64 + b] = hb16;
    } else {
      atomicAdd(&outsum[(size_t)t_in*32768 + (size_t)kj*64 + b], h);
    }
  }
  cstore[((size_t)(layer*2 + d)*512 + jbase + jj)*64 + b] = creg;
}

// ---- Fused dispatch: blocks 0..255 = recurrence; blocks 256..511 = next-chunk GEMM.
// GEMM half never polls -> no deadlock; any two WGs co-reside (53KB LDS).
__global__ void __launch_bounds__(256, 2) fused_step(
    const float* __restrict__ Whh, const float* __restrict__ xw_cur,
    float* __restrict__ xw_next,
    const float* __restrict__ gX32, const unsigned short* __restrict__ gXb,
    const float* __restrict__ gW, const float* __restrict__ gB,
    char* __restrict__ wsb,
    int rlayer, int rs0, int rsch,
    int gs0, int gsch, int gnjobs)
{
  extern __shared__ float lds[];
  if (blockIdx.x < NWG) {
    recur_body(Whh, xw_cur, wsb, rlayer, rs0, rsch, lds);
  } else {
    const int wg = blockIdx.x - NWG;
    float* Wt = lds;            // [128][68]
    float* Xt = lds + 128*68;   // [64][68]
    const int half = gnjobs >> 1;
    for (int job = wg; job < gnjobs; job += NWG) {
      const int dd  = (job >= half) ? 1 : 0;
      const int rem = job - (dd ? half : 0);
      const int sl  = rem >> 4;
      const int gt  = rem & 15;
      gemm_tile(gX32, gXb, gW, gB, xw_next, gs0, gsch, gt, sl, dd, Wt, Xt);
    }
  }
}

// ---- attention / output chain ----
__global__ void __launch_bounds__(256) attn_logits(const float* __restrict__ outsum,
                                                   const float* __restrict__ Wa,
                                                   const float* __restrict__ ba,
                                                   float* __restrict__ e) {
  __shared__ float part[4*64];
  const int t = blockIdx.x;
  const int b = threadIdx.x & 63, jq = threadIdx.x >> 6;
  const float* base = outsum + (size_t)t * 512 * 64;
  float acc = 0.0f;
  for (int j = jq*128; j < jq*128 + 128; ++j)
    acc += base[j*64 + b] * Wa[j];
  part[jq*64 + b] = acc;
  __syncthreads();
  if (threadIdx.x < 64) {
    const int bb = threadIdx.x;
    e[bb*512 + t] = part[0*64+bb] + part[1*64+bb] + part[2*64+bb] + part[3*64+bb] + ba[0];
  }
}

__global__ void __launch_bounds__(256) attn_softmax(const float* __restrict__ e,
                                                    float* __restrict__ attn,
                                                    float* __restrict__ aT) {
  __shared__ float red[256];
  const int b = blockIdx.x, tid = threadIdx.x;
  const float v0 = e[b*512 + tid];
  const float v1 = e[b*512 + 256 + tid];
  red[tid] = fmaxf(v0, v1);
  __syncthreads();
  for (int st = 128; st; st >>= 1) { if (tid < st) red[tid] = fmaxf(red[tid], red[tid+st]); __syncthreads(); }
  const float M = red[0];
  __syncthreads();
  const float e0 = __expf(v0 - M), e1 = __expf(v1 - M);
  red[tid] = e0 + e1;
  __syncthreads();
  for (int st = 128; st; st >>= 1) { if (tid < st) red[tid] += red[tid+st]; __syncthreads(); }
  const float inv = 1.0f / red[0];
  const float a0 = e0*inv, a1 = e1*inv;
  attn[b*512 + tid]       = a0;
  attn[b*512 + 256 + tid] = a1;
  aT[tid*64 + b]       = a0;
  aT[(256+tid)*64 + b] = a1;
}

__global__ void __launch_bounds__(256) attn_pool(const float* __restrict__ outsum,
                                                 const float* __restrict__ aT,
                                                 float* __restrict__ pooled) {
  const int tid = threadIdx.x;
  const int b = tid & 63, jj = tid >> 6;
  const int j = blockIdx.x*4 + jj;
  float acc = 0.0f;
  #pragma unroll 4
  for (int t = 0; t < 512; ++t)
    acc += aT[t*64 + b] * outsum[((size_t)t*512 + j)*64 + b];
  pooled[j*64 + b] = acc;
}

__global__ void __launch_bounds__(128) pred_kern(const float* __restrict__ pooled,
                                                 const float* __restrict__ Wo,
                                                 const float* __restrict__ bo,
                                                 float* __restrict__ out) {
  const int b = blockIdx.x, o = threadIdx.x;
  float acc = bo[o];
  const float* wr = Wo + o*512;
  #pragma unroll 4
  for (int j = 0; j < 512; j += 4) {
    const float4 w = *(const float4*)(wr + j);
    acc += w.x*pooled[(j+0)*64 + b] + w.y*pooled[(j+1)*64 + b]
         + w.z*pooled[(j+2)*64 + b] + w.w*pooled[(j+3)*64 + b];
  }
  out[b*128 + o] = acc;
}

extern "C" void kernel_launch(void* const* d_in, const int* in_sizes, int n_in,
                              void* d_out, int out_size, void* d_ws, size_t ws_size,
                              hipStream_t stream) {
  (void)in_sizes; (void)n_in; (void)out_size; (void)ws_size;
  const float* x    = (const float*)d_in[0];
  const float* Wih0 = (const float*)d_in[1];
  const float* Whh0 = (const float*)d_in[2];
  const float* b0   = (const float*)d_in[3];
  const float* Wih1 = (const float*)d_in[4];
  const float* Whh1 = (const float*)d_in[5];
  const float* b1   = (const float*)d_in[6];
  const float* Wa   = (const float*)d_in[7];
  const float* ba   = (const float*)d_in[8];
  const float* Wo   = (const float*)d_in[9];
  const float* bo   = (const float*)d_in[10];
  float* out = (float*)d_out;
  char* wsb  = (char*)d_ws;

  // zero hbuf + cstore + flags (contiguous)
  hipMemsetAsync(wsb + OFF_HBUF, 0, SZ_HBUF + SZ_CST + SZ_FLG, stream);

  float* xw0[2] = { (float*)(wsb + OFF_OUT), (float*)(wsb + OFF_OUT + SZB0) };
  float* xw1[2] = { (float*)(wsb + OFF_XW1), (float*)(wsb + OFF_XW1 + SZB1) };
  const unsigned short* h0p = (const unsigned short*)(wsb + OFF_H0);

  // layer-0 chunk-0 xw prologue
  xw_gemm<<<dim3(16, SCH0, 2), 256, 0, stream>>>(x, nullptr, Wih0, b0, xw0[0], 0, SCH0);

  // layer 0: fused recurrence + next-chunk GEMM (last dispatch runs no gemm)
  for (int c = 0; c < NCH0; ++c) {
    const bool last = (c == NCH0 - 1);
    fused_step<<<dim3(2*NWG), dim3(256), FUSED_LDS, stream>>>(
        Whh0, xw0[c & 1], xw0[(c + 1) & 1],
        x, nullptr, Wih0, b0,
        wsb, 0, c*SCH0, SCH0,
        (c + 1)*SCH0, SCH0, last ? 0 : 16*SCH0*2);
  }

  // layer-1 chunk-0 xw (needs ALL of h0 -> standalone, dispatch-ordered)
  xw_gemm<<<dim3(16, SCH1, 2), 256, 0, stream>>>(nullptr, h0p, Wih1, b1, xw1[0], 0, SCH1);

  // outsum becomes live now; zero it (xw0 double buffer no longer needed)
  hipMemsetAsync(wsb + OFF_OUT, 0, SZ_OUT, stream);

  // layer 1
  for (int c = 0; c < NCH1; ++c) {
    const bool last = (c == NCH1 - 1);
    fused_step<<<dim3(2*NWG), dim3(256), FUSED_LDS, stream>>>(
        Whh1, xw1[c & 1], xw1[(c + 1) & 1],
        nullptr, h0p, Wih1, b1,
        wsb, 1, c*SCH1, SCH1,
        (c + 1)*SCH1, SCH1, last ? 0 : 16*SCH1*2);
  }

  attn_logits <<<512, 256, 0, stream>>>((float*)(wsb + OFF_OUT), Wa, ba, (float*)(wsb + OFF_E));
  attn_softmax<<< 64, 256, 0, stream>>>((float*)(wsb + OFF_E), out + 8192, (float*)(wsb + OFF_AT));
  attn_pool   <<<128, 256, 0, stream>>>((float*)(wsb + OFF_OUT), (float*)(wsb + OFF_AT),
                                        (float*)(wsb + OFF_POOL));
  pred_kern   <<< 64, 128, 0, stream>>>((float*)(wsb + OFF_POOL), Wo, bo, out);
}

// Round 6
// 8367.265 us; speedup vs baseline: 1.6679x; 1.0824x over previous
//
#include <hip/hip_runtime.h>
#include <cstdint>
#include <cstddef>

#define TT 512
#define NWG 256
#define SCH0 32
#define NCH0 16
#define SCH1 16
#define NCH1 32

// ---- Workspace layout (BYTE offsets) — identical region sizes to baseline (~165 MiB).
#define OFF_H0   0ul
#define SZ_H0    (512ul*1024ul*64ul*2ul)          /* layer0 out, bf16 (T,1024,B) 64MiB */
#define OFF_OUT  (OFF_H0 + SZ_H0)
#define SZ_OUT   (512ul*512ul*64ul*4ul)           /* l1 fwd+bwd sum fp32; ALSO l0 xw dbuf */
#define OFF_XW1  (OFF_OUT + SZ_OUT)
#define SZ_XW1   (2ul*32ul*2048ul*64ul*4ul)       /* layer1 xw double buffer, 32MiB */
#define OFF_HBUF (OFF_XW1 + SZ_XW1)
#define SZ_HBUF  (2ul*2ul*2ul*512ul*64ul*4ul)     /* [layer][pp][dir] packed-h u32 [k/2][b][2] */
#define OFF_CST  (OFF_HBUF + SZ_HBUF)
#define SZ_CST   (2ul*2ul*512ul*64ul*4ul)
#define OFF_FLG  (OFF_CST + SZ_CST)
#define SZ_FLG   (2ul*2ul*512ul*128ul*4ul)        /* u32 flags [layer][dir][step][slot] */
#define OFF_E    (OFF_FLG + SZ_FLG)
#define SZ_E     (64ul*512ul*4ul)
#define OFF_AT   (OFF_E + SZ_E)
#define SZ_AT    (512ul*64ul*4ul)
#define OFF_POOL (OFF_AT + SZ_AT)
#define SZ_POOL  (512ul*64ul*4ul)

#define SZB0 (2ul*(size_t)SCH0*2048ul*64ul*4ul)   /* 33.5MB l0 xw chunk; 2 fit in SZ_OUT */
#define SZB1 (2ul*(size_t)SCH1*2048ul*64ul*4ul)   /* 16.8MB l1 xw chunk; 2 fit in SZ_XW1 */

#define FUSED_LDS 53248   /* recur 32KB; gemm f32 52.2KB; gemm mfma 40KB */

typedef unsigned long long u64;
typedef __attribute__((ext_vector_type(8))) short short8v;   // bf16x8 MFMA frag (4 VGPR)
typedef __attribute__((ext_vector_type(4))) float f32x4;     // MFMA C/D frag

#define AHL(p) __hip_atomic_load((p), __ATOMIC_RELAXED, __HIP_MEMORY_SCOPE_AGENT)

__device__ __forceinline__ unsigned short f2bf(float f) {   // RNE bf16
  unsigned u = __float_as_uint(f);
  u += 0x7fffu + ((u >> 16) & 1u);
  return (unsigned short)(u >> 16);
}

// ---- layer-0 xW GEMM tile (fp32 VALU path; input x fp32, K=256). UNCHANGED.
__device__ __forceinline__ void gemm_tile_f32(const float* __restrict__ X32,
                                              const float* __restrict__ W,
                                              const float* __restrict__ bias,
                                              float* __restrict__ xwout,
                                              int s0, int sch, int gtile, int sl, int d,
                                              float* Wt, float* Xt) {
  const int K = 256;
  const int tid = threadIdx.x;
  const int sg = s0 + sl;
  const int t = d ? (511 - sg) : sg;
  const int gq = tid >> 4, bq = tid & 15;
  const int g0 = gtile*128 + gq*8;

  float acc[8][4];
  #pragma unroll
  for (int i = 0; i < 8; ++i) {
    const float bv = bias[d*2048 + g0 + i];
    acc[i][0]=bv; acc[i][1]=bv; acc[i][2]=bv; acc[i][3]=bv;
  }
  const float* Wbase = W + ((size_t)d*2048 + gtile*128)*K;

  for (int kc = 0; kc < K; kc += 64) {
    __syncthreads();
    #pragma unroll
    for (int i = 0; i < 8; ++i) {
      const int f4 = i*256 + tid;
      const int row = f4 >> 4, kk4 = (f4 & 15) << 2;
      const int kk4s = kk4 ^ (((row >> 3) & 3) << 2);
      *(float4*)(Wt + row*68 + kk4s) = *(const float4*)(Wbase + (size_t)row*K + kc + kk4);
    }
    {
      const int bb = tid >> 2, kq = tid & 3;
      const float* src = X32 + ((size_t)t*64 + bb)*256 + kc + kq*16;
      #pragma unroll
      for (int i = 0; i < 4; ++i) {
        const float4 v = *(const float4*)(src + i*4);
        const int k = kq*16 + i*4;
        Xt[(k+0)*68 + bb] = v.x;
        Xt[(k+1)*68 + bb] = v.y;
        Xt[(k+2)*68 + bb] = v.z;
        Xt[(k+3)*68 + bb] = v.w;
      }
    }
    __syncthreads();
    for (int k4 = 0; k4 < 64; k4 += 4) {
      float4 w[8];
      #pragma unroll
      for (int i = 0; i < 8; ++i) {
        const int row = gq*8 + i;
        const int k4s = k4 ^ (((row >> 3) & 3) << 2);
        w[i] = *(const float4*)(Wt + row*68 + k4s);
      }
      float4 xv[4];
      #pragma unroll
      for (int kk = 0; kk < 4; ++kk) xv[kk] = *(const float4*)(Xt + (k4+kk)*68 + bq*4);
      #pragma unroll
      for (int i = 0; i < 8; ++i) {
        acc[i][0] += w[i].x*xv[0].x + w[i].y*xv[1].x + w[i].z*xv[2].x + w[i].w*xv[3].x;
        acc[i][1] += w[i].x*xv[0].y + w[i].y*xv[1].y + w[i].z*xv[2].y + w[i].w*xv[3].y;
        acc[i][2] += w[i].x*xv[0].z + w[i].y*xv[1].z + w[i].z*xv[2].z + w[i].w*xv[3].z;
        acc[i][3] += w[i].x*xv[0].w + w[i].y*xv[1].w + w[i].z*xv[2].w + w[i].w*xv[3].w;
      }
    }
  }
  float* op = xwout + (((size_t)d*sch + sl)*2048 + g0)*64 + bq*4;
  #pragma unroll
  for (int i = 0; i < 8; ++i)
    *(float4*)(op + (size_t)i*64) = make_float4(acc[i][0],acc[i][1],acc[i][2],acc[i][3]);
}

// ---- layer-1 xW GEMM tile (MFMA split-bf16; input h0 bf16, K=1024).
// xw[g][b] = bias + sum_k W[g][k] X[t][k][b].  W -> Wb+Wr (bf16 value+residual),
// X exact bf16 => Wb.X + Wr.X is fp32-grade (~1e-5).  Fragment layout carried
// verbatim from the round-4-verified recurrence: A lane(lhi,lcol) holds m=lcol,
// k=(ks*4+lhi)*8+e; C row=lhi*4+reg, col=lcol.  LDS A rows octet-XOR-swizzled
// (os = o ^ (row&7)) -> ds_read_b128 spans all 32 banks, 2-way (free).
__device__ __forceinline__ void gemm_tile_mfma(const unsigned short* __restrict__ Xb,
                                               const float* __restrict__ W,
                                               const float* __restrict__ bias,
                                               float* __restrict__ xwout,
                                               int s0, int sch, int gtile, int sl, int d,
                                               unsigned short* aWb, unsigned short* aWr,
                                               unsigned short* aX) {
  const int K = 1024;
  const int tid = threadIdx.x;
  const int sg = s0 + sl;
  const int t = d ? (511 - sg) : sg;
  const int w = tid >> 6, lane = tid & 63;
  const int lhi = lane >> 4, lcol = lane & 15;
  const int g0 = gtile*128;
  const float* Wbase = W + ((size_t)d*2048 + g0)*K;
  const unsigned short* Xbase = Xb + (size_t)t*K*64;

  f32x4 acc[8];
  #pragma unroll
  for (int mt = 0; mt < 8; ++mt) acc[mt] = (f32x4){0.f,0.f,0.f,0.f};

  for (int kc = 0; kc < K; kc += 64) {
    __syncthreads();
    // stage W: 128 rows x 64 k fp32 -> split-bf16, octet-swizzled [row][os*8+e]
    #pragma unroll
    for (int i = 0; i < 4; ++i) {
      const int p = i*256 + tid;
      const int row = p >> 3, o = p & 7;
      const float* src = Wbase + (size_t)row*K + kc + o*8;
      const float4 v0 = *(const float4*)(src);
      const float4 v1 = *(const float4*)(src + 4);
      const float f[8] = {v0.x,v0.y,v0.z,v0.w,v1.x,v1.y,v1.z,v1.w};
      short8v vb, vr;
      #pragma unroll
      for (int e = 0; e < 8; ++e) {
        const unsigned short hb = f2bf(f[e]);
        vb[e] = (short)hb;
        vr[e] = (short)f2bf(f[e] - __uint_as_float((unsigned)hb << 16));
      }
      const int os = o ^ (row & 7);
      *(short8v*)(aWb + (size_t)row*64 + os*8) = vb;
      *(short8v*)(aWr + (size_t)row*64 + os*8) = vr;
    }
    // stage X: 64 k x 64 b bf16 -> B-frag layout aX[o][b][e] (k-transpose)
    #pragma unroll
    for (int i = 0; i < 4; ++i) {
      const int p = i*256 + tid;
      const int k = p >> 4, b4 = (p & 15) << 2;
      const uint2 r = *(const uint2*)(Xbase + (size_t)(kc + k)*64 + b4);
      const int o = k >> 3, e = k & 7;
      aX[((o*64 + b4+0)<<3) + e] = (unsigned short)(r.x & 0xffffu);
      aX[((o*64 + b4+1)<<3) + e] = (unsigned short)(r.x >> 16);
      aX[((o*64 + b4+2)<<3) + e] = (unsigned short)(r.y & 0xffffu);
      aX[((o*64 + b4+3)<<3) + e] = (unsigned short)(r.y >> 16);
    }
    __syncthreads();
    #pragma unroll
    for (int ks = 0; ks < 2; ++ks) {
      union { short8v v; } bx;
      bx.v = *(const short8v*)(aX + (((ks*4 + lhi)*64) + w*16 + lcol)*8);
      #pragma unroll
      for (int mt = 0; mt < 8; ++mt) {
        const int row = mt*16 + lcol;
        const int os = (ks*4 + lhi) ^ (row & 7);
        const short8v ab = *(const short8v*)(aWb + (size_t)row*64 + os*8);
        const short8v ar = *(const short8v*)(aWr + (size_t)row*64 + os*8);
        acc[mt] = __builtin_amdgcn_mfma_f32_16x16x32_bf16(ab, bx.v, acc[mt], 0, 0, 0);
        acc[mt] = __builtin_amdgcn_mfma_f32_16x16x32_bf16(ar, bx.v, acc[mt], 0, 0, 0);
      }
    }
  }
  float* op = xwout + (((size_t)d*sch + sl)*2048 + g0)*64 + w*16 + lcol;
  const float* bp = bias + d*2048 + g0;
  #pragma unroll
  for (int mt = 0; mt < 8; ++mt) {
    #pragma unroll
    for (int r = 0; r < 4; ++r) {
      const int grow = mt*16 + lhi*4 + r;
      op[(size_t)grow*64] = acc[mt][r] + bp[grow];
    }
  }
}

__device__ __forceinline__ void gemm_tile(const float* __restrict__ X32,
                                          const unsigned short* __restrict__ Xb,
                                          const float* __restrict__ W,
                                          const float* __restrict__ bias,
                                          float* __restrict__ xwout,
                                          int s0, int sch, int gtile, int sl, int d,
                                          float* lds) {
  if (X32) {
    gemm_tile_f32(X32, W, bias, xwout, s0, sch, gtile, sl, d, lds, lds + 128*68);
  } else {
    unsigned short* aWb = (unsigned short*)lds;       // [128][64] 16KB
    unsigned short* aWr = aWb + 8192;                 // 16KB
    unsigned short* aX  = aWr + 8192;                 // [8][64][8] 8KB
    gemm_tile_mfma(Xb, W, bias, xwout, s0, sch, gtile, sl, d, aWb, aWr, aX);
  }
}

// standalone GEMM dispatch (layer-0 chunk 0 prologue; layer-1 chunk 0 between layers).
// layer-1 chunk 0 CANNOT be fused into the last layer-0 dispatch: every job reads h0
// rows written by the FINAL layer-0 steps -> in-dispatch race (round-1 failure).
__global__ void __launch_bounds__(256) xw_gemm(const float* __restrict__ X32,
                                               const unsigned short* __restrict__ Xb,
                                               const float* __restrict__ W,
                                               const float* __restrict__ bias,
                                               float* __restrict__ xwout,
                                               int s0, int sch) {
  __shared__ float lds_s[13056];
  gemm_tile(X32, Xb, W, bias, xwout, s0, sch, blockIdx.x, blockIdx.y, blockIdx.z, lds_s);
}

// ---- Recurrent body (round-4, UNCHANGED): gates[16 m][64 b] = Whh16 x h via
// MFMA 16x16x32 bf16 split-bf16 (Wb.hb + Wb.rb + Wr.hb). Lane-local epilogue,
// 2 barriers/step, round-2 handshake (tid<128 poll + B0, Bend drain, tid0 flag).
__device__ __forceinline__ void recur_body(
    const float* __restrict__ Whh, const float* __restrict__ xw,
    char* __restrict__ wsb, int layer, int s0, int sch, float* lds)
{
  unsigned short* alds = (unsigned short*)lds;   // [2 part][16 ks][4 oct][16 slot][8 e] bf16 = 32KB

  unsigned short* h0 = (unsigned short*)(wsb + OFF_H0);
  float* outsum  = (float*)(wsb + OFF_OUT);
  unsigned* hbase = (unsigned*)(wsb + OFF_HBUF) + (size_t)layer*131072;
  float* cstore  = (float*)(wsb + OFF_CST);
  unsigned* flg  = (unsigned*)(wsb + OFF_FLG);

  const int tid = threadIdx.x;
  const int d     = blockIdx.x >> 7;
  const int slot  = blockIdx.x & 127;
  const int jbase = slot << 2;

  const int w    = tid >> 6;          // wave -> 16-batch column block
  const int lane = tid & 63;
  const int lhi  = lane >> 4;
  const int lcol = lane & 15;
  const int jj   = lhi;               // epilogue j index (C row group)
  const int b    = w*16 + lcol;       // epilogue batch (C col)

  __builtin_amdgcn_s_setprio(1);      // recurrence waves preferred over gemm waves

  // stage Whh as split-bf16 MFMA A-fragments. element (m,k) at
  // [part][k>>5][(k>>3)&3][m ^ ((k>>3)&3)][k&7]  (XOR de-conflicts b128 reads)
  for (int m = 0; m < 16; ++m) {
    const int g = m & 3, j = m >> 2;
    const float* src = Whh + ((size_t)d*2048 + g*512 + jbase + j)*512;
    for (int k = tid; k < 512; k += 256) {
      const float wv = src[k];
      const unsigned short wb = f2bf(wv);
      const unsigned short wr = f2bf(wv - __uint_as_float((unsigned)wb << 16));
      const int oct = (k >> 3) & 3;
      const int idx = (((k >> 5)*4 + oct)*16 + (m ^ oct))*8 + (k & 7);
      alds[idx] = wb;
      alds[8192 + idx] = wr;
    }
  }
  float creg = cstore[((size_t)(layer*2 + d)*512 + jbase + jj)*64 + b];
  __syncthreads();

  const unsigned fbase = (unsigned)(layer*2 + d) * 512u;

  for (int sl = 0; sl < sch; ++sl) {
    const int sg = s0 + sl;
    const int t_in = d ? (511 - sg) : sg;

    // xw preacts are h-independent: issue before the poll (latency hides there)
    const float* xwp = xw + ((size_t)(d*sch + sl)*2048 + (size_t)(jbase + jj))*64 + b;
    const float px0 = xwp[0];
    const float px1 = xwp[32768];
    const float px2 = xwp[65536];
    const float px3 = xwp[98304];

    if (sg > 0) {
      if (tid < 128) {   // proven round-2 poll: 1 flag/lane, relaxed agent
        unsigned* p = &flg[(size_t)(fbase + (unsigned)sg - 1u)*128 + tid];
        while (AHL(p) == 0u) __builtin_amdgcn_s_sleep(1);
      }
      __syncthreads();   // B0
    }

    const u64* hsrc = (const u64*)(hbase + ((sg & 1)*2 + d)*32768);

    // B operand ring: per ks, 4 u64 = 8 packed dwords = elements e0..7 for col b.
    u64 ring[8][4];
    #pragma unroll
    for (int ks = 0; ks < 8; ++ks) {
      const size_t hb0 = (size_t)((ks*4 + lhi)*4)*64 + b;
      ring[ks][0] = AHL(hsrc + hb0);
      ring[ks][1] = AHL(hsrc + hb0 + 64);
      ring[ks][2] = AHL(hsrc + hb0 + 128);
      ring[ks][3] = AHL(hsrc + hb0 + 192);
    }

    f32x4 acc = {0.f, 0.f, 0.f, 0.f};
    #pragma unroll
    for (int ks = 0; ks < 16; ++ks) {
      const u64 q0 = ring[ks & 7][0], q1 = ring[ks & 7][1];
      const u64 q2 = ring[ks & 7][2], q3 = ring[ks & 7][3];
      if (ks < 8) {
        const size_t hb2 = (size_t)(((ks + 8)*4 + lhi)*4)*64 + b;
        ring[ks][0] = AHL(hsrc + hb2);
        ring[ks][1] = AHL(hsrc + hb2 + 64);
        ring[ks][2] = AHL(hsrc + hb2 + 128);
        ring[ks][3] = AHL(hsrc + hb2 + 192);
      }
      // unpack packed (hb<<16)|rb dwords into value/residual bf16 fragments
      union { unsigned u[4]; short8v v; } hb, rb;
      hb.u[0] = __builtin_amdgcn_perm((unsigned)(q0 >> 32), (unsigned)q0, 0x07060302u);
      rb.u[0] = __builtin_amdgcn_perm((unsigned)(q0 >> 32), (unsigned)q0, 0x05040100u);
      hb.u[1] = __builtin_amdgcn_perm((unsigned)(q1 >> 32), (unsigned)q1, 0x07060302u);
      rb.u[1] = __builtin_amdgcn_perm((unsigned)(q1 >> 32), (unsigned)q1, 0x05040100u);
      hb.u[2] = __builtin_amdgcn_perm((unsigned)(q2 >> 32), (unsigned)q2, 0x07060302u);
      rb.u[2] = __builtin_amdgcn_perm((unsigned)(q2 >> 32), (unsigned)q2, 0x05040100u);
      hb.u[3] = __builtin_amdgcn_perm((unsigned)(q3 >> 32), (unsigned)q3, 0x07060302u);
      rb.u[3] = __builtin_amdgcn_perm((unsigned)(q3 >> 32), (unsigned)q3, 0x05040100u);
      const int abase = ((ks*4 + lhi)*16 + (lcol ^ lhi))*8;
      const short8v ab = *(const short8v*)(alds + abase);
      const short8v ar = *(const short8v*)(alds + 8192 + abase);
      acc = __builtin_amdgcn_mfma_f32_16x16x32_bf16(ab, hb.v, acc, 0, 0, 0);
      acc = __builtin_amdgcn_mfma_f32_16x16x32_bf16(ab, rb.v, acc, 0, 0, 0);
      acc = __builtin_amdgcn_mfma_f32_16x16x32_bf16(ar, hb.v, acc, 0, 0, 0);
      // dropped Wr*rb term: ~4e-6 relative
    }

    // epilogue: lane-local gates (acc[r] = gate r of j = jbase+jj, batch b)
    const float pi = acc[0] + px0;
    const float pf = acc[1] + px1;
    const float pg = acc[2] + px2;
    const float po = acc[3] + px3;
    const float iv = 1.0f/(1.0f + __expf(-pi));
    const float fv = 1.0f/(1.0f + __expf(-pf));
    const float gv = tanhf(pg);
    const float ov = 1.0f/(1.0f + __expf(-po));
    float cc2 = fv*creg + iv*gv;
    cc2 = fminf(fmaxf(cc2, -100.0f), 100.0f);
    creg = cc2;
    const float h = ov*tanhf(cc2);

    const unsigned short hb16 = f2bf(h);
    const unsigned short rb16 = f2bf(h - __uint_as_float((unsigned)hb16 << 16));
    const unsigned hpk = ((unsigned)hb16 << 16) | (unsigned)rb16;
    unsigned* hout = hbase + (((sg & 1) ^ 1)*2 + d)*32768;
    const int kj = jbase + jj;
    __hip_atomic_store(hout + ((size_t)(kj >> 1)*128 + b*2 + (kj & 1)), hpk,
                       __ATOMIC_RELAXED, __HIP_MEMORY_SCOPE_AGENT);

    __syncthreads();   // Bend: drains each wave's vmcnt -> h stores ACKed
    if (tid == 0)
      __hip_atomic_store(&flg[(size_t)(fbase + (unsigned)sg)*128 + slot], 1u,
                         __ATOMIC_RELAXED, __HIP_MEMORY_SCOPE_AGENT);
    // deferred: consumed only across dispatch boundaries -> off the critical
    // edge; their ACK folds into the NEXT step's Bend (poll interval >> ACK).
    if (layer == 0) {
      h0[(size_t)t_in*65536 + (size_t)(d*512 + kj)*64 + b] = hb16;
    } else {
      atomicAdd(&outsum[(size_t)t_in*32768 + (size_t)kj*64 + b], h);
    }
  }
  cstore[((size_t)(layer*2 + d)*512 + jbase + jj)*64 + b] = creg;
}

// ---- Fused dispatch: blocks 0..255 = recurrence; blocks 256..511 = next-chunk GEMM.
// GEMM half never polls -> no deadlock; any two WGs co-reside (<=53KB LDS each).
__global__ void __launch_bounds__(256, 2) fused_step(
    const float* __restrict__ Whh, const float* __restrict__ xw_cur,
    float* __restrict__ xw_next,
    const float* __restrict__ gX32, const unsigned short* __restrict__ gXb,
    const float* __restrict__ gW, const float* __restrict__ gB,
    char* __restrict__ wsb,
    int rlayer, int rs0, int rsch,
    int gs0, int gsch, int gnjobs)
{
  extern __shared__ float lds[];
  if (blockIdx.x < NWG) {
    recur_body(Whh, xw_cur, wsb, rlayer, rs0, rsch, lds);
  } else {
    const int wg = blockIdx.x - NWG;
    const int half = gnjobs >> 1;
    for (int job = wg; job < gnjobs; job += NWG) {
      const int dd  = (job >= half) ? 1 : 0;
      const int rem = job - (dd ? half : 0);
      const int sl  = rem >> 4;
      const int gt  = rem & 15;
      gemm_tile(gX32, gXb, gW, gB, xw_next, gs0, gsch, gt, sl, dd, lds);
    }
  }
}

// ---- attention / output chain ----
__global__ void __launch_bounds__(256) attn_logits(const float* __restrict__ outsum,
                                                   const float* __restrict__ Wa,
                                                   const float* __restrict__ ba,
                                                   float* __restrict__ e) {
  __shared__ float part[4*64];
  const int t = blockIdx.x;
  const int b = threadIdx.x & 63, jq = threadIdx.x >> 6;
  const float* base = outsum + (size_t)t * 512 * 64;
  float acc = 0.0f;
  for (int j = jq*128; j < jq*128 + 128; ++j)
    acc += base[j*64 + b] * Wa[j];
  part[jq*64 + b] = acc;
  __syncthreads();
  if (threadIdx.x < 64) {
    const int bb = threadIdx.x;
    e[bb*512 + t] = part[0*64+bb] + part[1*64+bb] + part[2*64+bb] + part[3*64+bb] + ba[0];
  }
}

__global__ void __launch_bounds__(256) attn_softmax(const float* __restrict__ e,
                                                    float* __restrict__ attn,
                                                    float* __restrict__ aT) {
  __shared__ float red[256];
  const int b = blockIdx.x, tid = threadIdx.x;
  const float v0 = e[b*512 + tid];
  const float v1 = e[b*512 + 256 + tid];
  red[tid] = fmaxf(v0, v1);
  __syncthreads();
  for (int st = 128; st; st >>= 1) { if (tid < st) red[tid] = fmaxf(red[tid], red[tid+st]); __syncthreads(); }
  const float M = red[0];
  __syncthreads();
  const float e0 = __expf(v0 - M), e1 = __expf(v1 - M);
  red[tid] = e0 + e1;
  __syncthreads();
  for (int st = 128; st; st >>= 1) { if (tid < st) red[tid] += red[tid+st]; __syncthreads(); }
  const float inv = 1.0f / red[0];
  const float a0 = e0*inv, a1 = e1*inv;
  attn[b*512 + tid]       = a0;
  attn[b*512 + 256 + tid] = a1;
  aT[tid*64 + b]       = a0;
  aT[(256+tid)*64 + b] = a1;
}

__global__ void __launch_bounds__(256) attn_pool(const float* __restrict__ outsum,
                                                 const float* __restrict__ aT,
                                                 float* __restrict__ pooled) {
  const int tid = threadIdx.x;
  const int b = tid & 63, jj = tid >> 6;
  const int j = blockIdx.x*4 + jj;
  float acc = 0.0f;
  #pragma unroll 4
  for (int t = 0; t < 512; ++t)
    acc += aT[t*64 + b] * outsum[((size_t)t*512 + j)*64 + b];
  pooled[j*64 + b] = acc;
}

__global__ void __launch_bounds__(128) pred_kern(const float* __restrict__ pooled,
                                                 const float* __restrict__ Wo,
                                                 const float* __restrict__ bo,
                                                 float* __restrict__ out) {
  const int b = blockIdx.x, o = threadIdx.x;
  float acc = bo[o];
  const float* wr = Wo + o*512;
  #pragma unroll 4
  for (int j = 0; j < 512; j += 4) {
    const float4 w = *(const float4*)(wr + j);
    acc += w.x*pooled[(j+0)*64 + b] + w.y*pooled[(j+1)*64 + b]
         + w.z*pooled[(j+2)*64 + b] + w.w*pooled[(j+3)*64 + b];
  }
  out[b*128 + o] = acc;
}

extern "C" void kernel_launch(void* const* d_in, const int* in_sizes, int n_in,
                              void* d_out, int out_size, void* d_ws, size_t ws_size,
                              hipStream_t stream) {
  (void)in_sizes; (void)n_in; (void)out_size; (void)ws_size;
  const float* x    = (const float*)d_in[0];
  const float* Wih0 = (const float*)d_in[1];
  const float* Whh0 = (const float*)d_in[2];
  const float* b0   = (const float*)d_in[3];
  const float* Wih1 = (const float*)d_in[4];
  const float* Whh1 = (const float*)d_in[5];
  const float* b1   = (const float*)d_in[6];
  const float* Wa   = (const float*)d_in[7];
  const float* ba   = (const float*)d_in[8];
  const float* Wo   = (const float*)d_in[9];
  const float* bo   = (const float*)d_in[10];
  float* out = (float*)d_out;
  char* wsb  = (char*)d_ws;

  // zero hbuf + cstore + flags (contiguous)
  hipMemsetAsync(wsb + OFF_HBUF, 0, SZ_HBUF + SZ_CST + SZ_FLG, stream);

  float* xw0[2] = { (float*)(wsb + OFF_OUT), (float*)(wsb + OFF_OUT + SZB0) };
  float* xw1[2] = { (float*)(wsb + OFF_XW1), (float*)(wsb + OFF_XW1 + SZB1) };
  const unsigned short* h0p = (const unsigned short*)(wsb + OFF_H0);

  // layer-0 chunk-0 xw prologue (fp32 path)
  xw_gemm<<<dim3(16, SCH0, 2), 256, 0, stream>>>(x, nullptr, Wih0, b0, xw0[0], 0, SCH0);

  // layer 0: fused recurrence + next-chunk GEMM (last dispatch runs no gemm)
  for (int c = 0; c < NCH0; ++c) {
    const bool last = (c == NCH0 - 1);
    fused_step<<<dim3(2*NWG), dim3(256), FUSED_LDS, stream>>>(
        Whh0, xw0[c & 1], xw0[(c + 1) & 1],
        x, nullptr, Wih0, b0,
        wsb, 0, c*SCH0, SCH0,
        (c + 1)*SCH0, SCH0, last ? 0 : 16*SCH0*2);
  }

  // layer-1 chunk-0 xw (needs ALL of h0 -> standalone, dispatch-ordered; MFMA path)
  xw_gemm<<<dim3(16, SCH1, 2), 256, 0, stream>>>(nullptr, h0p, Wih1, b1, xw1[0], 0, SCH1);

  // outsum becomes live now; zero it (xw0 double buffer no longer needed)
  hipMemsetAsync(wsb + OFF_OUT, 0, SZ_OUT, stream);

  // layer 1 (gemm half uses MFMA path: gX32 = nullptr)
  for (int c = 0; c < NCH1; ++c) {
    const bool last = (c == NCH1 - 1);
    fused_step<<<dim3(2*NWG), dim3(256), FUSED_LDS, stream>>>(
        Whh1, xw1[c & 1], xw1[(c + 1) & 1],
        nullptr, h0p, Wih1, b1,
        wsb, 1, c*SCH1, SCH1,
        (c + 1)*SCH1, SCH1, last ? 0 : 16*SCH1*2);
  }

  attn_logits <<<512, 256, 0, stream>>>((float*)(wsb + OFF_OUT), Wa, ba, (float*)(wsb + OFF_E));
  attn_softmax<<< 64, 256, 0, stream>>>((float*)(wsb + OFF_E), out + 8192, (float*)(wsb + OFF_AT));
  attn_pool   <<<128, 256, 0, stream>>>((float*)(wsb + OFF_OUT), (float*)(wsb + OFF_AT),
                                        (float*)(wsb + OFF_POOL));
  pred_kern   <<< 64, 128, 0, stream>>>((float*)(wsb + OFF_POOL), Wo, bo, out);
}